// Round 12
// baseline (502.499 us; speedup 1.0000x reference)
//
#include <hip/hip_runtime.h>
#include <cstdint>

#define NNODES 10000
#define NEDGES 160000
#define TOT_E  (NEDGES + NNODES)
#define HEADS  8
#define MT 625        // NNODES/16 row-tiles (10000 = 625*16 exactly)

typedef unsigned short u16;
typedef __attribute__((ext_vector_type(8))) _Float16 h8;   // 8 fp16 (16B)
typedef __attribute__((ext_vector_type(4))) _Float16 h4;   // 4 fp16 (8B)
typedef __attribute__((ext_vector_type(4))) float f4;      // MFMA accumulator

__device__ inline u16 f2h(float x) {
    union { _Float16 h; u16 u; } c; c.h = (_Float16)x; return c.u;
}

// ---------------- CSR build (dst-sorted) ----------------
__global__ void count_k(const int* __restrict__ ei, int* __restrict__ deg) {
    int i = blockIdx.x * 256 + threadIdx.x;
    if (i >= TOT_E) return;
    int dst = (i < NEDGES) ? ei[NEDGES + i] : (i - NEDGES);
    atomicAdd(deg + dst, 1);
}

__global__ __launch_bounds__(1024) void scan_k(const int* __restrict__ deg,
                                               int* __restrict__ rows) {
    __shared__ int buf[1024];
    int tid = threadIdx.x;
    int base = tid * 10;
    int loc[10]; int s = 0;
    #pragma unroll
    for (int j = 0; j < 10; j++) {
        int i = base + j;
        loc[j] = s;
        s += (i < NNODES) ? deg[i] : 0;
    }
    buf[tid] = s;
    __syncthreads();
    for (int off = 1; off < 1024; off <<= 1) {
        int t = (tid >= off) ? buf[tid - off] : 0;
        __syncthreads();
        buf[tid] += t;
        __syncthreads();
    }
    int ex = tid ? buf[tid - 1] : 0;
    #pragma unroll
    for (int j = 0; j < 10; j++) {
        int i = base + j;
        if (i < NNODES) rows[i] = ex + loc[j];
    }
    if (tid == 1023) rows[NNODES] = buf[1023];
}

__global__ void scatter_k(const int* __restrict__ ei, const int* __restrict__ rows,
                          int* __restrict__ cursor, int* __restrict__ esrc) {
    int i = blockIdx.x * 256 + threadIdx.x;
    if (i >= TOT_E) return;
    int src, dst;
    if (i < NEDGES) { src = ei[i]; dst = ei[NEDGES + i]; }
    else            { src = i - NEDGES; dst = src; }
    int pos = atomicAdd(cursor + dst, 1);
    esrc[rows[dst] + pos] = src;
}

// ---------------- fp32 -> fp16 swizzled convert (fragment-major) ----------
// Layout: A'[tr][tk][lane][8] with row = tr*16 + (lane&15), k = tk*32 +
// (lane>>4)*8 + e  — exactly the 16x16x32 MFMA A/B-operand mapping, so the
// GEMM fragment load is one coalesced 1KB global_load_dwordx4 per wave.
template<int K, int KT>
__device__ inline void cvt_seg(const float* __restrict__ in, u16* __restrict__ out, int t) {
    int lane = t & 63;
    int tmp  = t >> 6;
    int tk   = tmp % KT;                   // KT pow2 -> and
    int tr   = tmp / KT;                   // KT pow2 -> shift
    const float* sp = in + (size_t)(tr * 16 + (lane & 15)) * K + tk * 32 + (lane >> 4) * 8;
    float4 v0 = *(const float4*)sp;
    float4 v1 = *(const float4*)(sp + 4);
    ushort4 h0{f2h(v0.x), f2h(v0.y), f2h(v0.z), f2h(v0.w)};
    ushort4 h1{f2h(v1.x), f2h(v1.y), f2h(v1.z), f2h(v1.w)};
    *(ushort4*)(out + (size_t)t * 8)     = h0;
    *(ushort4*)(out + (size_t)t * 8 + 4) = h1;
}

__global__ __launch_bounds__(256) void cvtsw_all(const float* __restrict__ x,
        const float* __restrict__ W1, const float* __restrict__ W2,
        const float* __restrict__ W3, u16* __restrict__ Axs, u16* __restrict__ W1s,
        u16* __restrict__ W2s, u16* __restrict__ W3s) {
    int g = blockIdx.x * 256 + threadIdx.x;
    if (g < 320000)      cvt_seg<256, 8>(x,  Axs, g);            // 625*8*64
    else if (g < 336384) cvt_seg<256, 8>(W1, W1s, g - 320000);   // 32*8*64
    else if (g < 401920) cvt_seg<512, 16>(W2, W2s, g - 336384);  // 64*16*64
    else                 cvt_seg<1024, 32>(W3, W3s, g - 401920); // 128*32*64
}

// ---------------- fat-wave direct-register fp16 GEMM -----------------------
// One 64-lane wave computes a full 128x128 tile (8x8 acc of 16x16). A and B
// are in fragment-major layout: frag load = 1 coalesced dwordx4/wave, straight
// to VGPR. NO LDS, NO barriers (the r7-r11 structure was LDS-read-BW-bound at
// ~21% MfmaUtil; this removes LDS and the 2x cross-wave read redundancy).
// Depth-1 manual pipeline (a1/b1 next-tile frags). ~440 VGPR -> 1 wave/SIMD;
// waves are independent so no TLP needed for barriers.
// Epilogue: fp16 C row-major + fused asrc/adst alpha partials (atomics).
template<int CHEAD>
__global__ __launch_bounds__(64) void gemm_dx(
    const u16* __restrict__ A, const u16* __restrict__ B,
    u16* __restrict__ C16, int N, int K,
    const float* __restrict__ a_s, const float* __restrict__ a_d,
    float* __restrict__ asrc, float* __restrict__ adst)
{
    const int lane = threadIdx.x;
    const int l15 = lane & 15, quad = lane >> 4;
    const int bx = blockIdx.x, by = blockIdx.y;
    const int row0 = by * 128, col0 = bx * 128;
    const int KT = K >> 5;                   // 8 / 16 / 32 (always even)
    const int lo = lane * 8;                 // lane offset within a fragment

    size_t abase[8], bbase[8];               // uniform -> SGPRs
    #pragma unroll
    for (int i = 0; i < 8; i++) {
        int tr = by * 8 + i; if (tr > MT - 1) tr = MT - 1;   // dup rows, stores masked
        abase[i] = (size_t)tr * KT * 512;
    }
    #pragma unroll
    for (int j = 0; j < 8; j++)
        bbase[j] = (size_t)(bx * 8 + j) * KT * 512;          // N mult of 128 -> valid

    f4 acc[8][8];
    #pragma unroll
    for (int i = 0; i < 8; i++)
        #pragma unroll
        for (int j = 0; j < 8; j++)
            acc[i][j] = (f4){0.f, 0.f, 0.f, 0.f};

    h8 a0[8], b0[8], a1[8], b1[8];
    #pragma unroll
    for (int i = 0; i < 8; i++) {
        a0[i] = *(const h8*)(A + abase[i] + lo);
        b0[i] = *(const h8*)(B + bbase[i] + lo);
    }

    for (int t = 0; t < KT; t += 2) {
        const int off1 = (t + 1) * 512 + lo;
        #pragma unroll
        for (int i = 0; i < 8; i++) {
            a1[i] = *(const h8*)(A + abase[i] + off1);
            b1[i] = *(const h8*)(B + bbase[i] + off1);
        }
        #pragma unroll
        for (int j = 0; j < 8; j++)
            #pragma unroll
            for (int i = 0; i < 8; i++)
                acc[i][j] = __builtin_amdgcn_mfma_f32_16x16x32_f16(a0[i], b0[j], acc[i][j], 0, 0, 0);
        if (t + 2 < KT) {
            const int off2 = (t + 2) * 512 + lo;
            #pragma unroll
            for (int i = 0; i < 8; i++) {
                a0[i] = *(const h8*)(A + abase[i] + off2);
                b0[i] = *(const h8*)(B + bbase[i] + off2);
            }
        }
        #pragma unroll
        for (int j = 0; j < 8; j++)
            #pragma unroll
            for (int i = 0; i < 8; i++)
                acc[i][j] = __builtin_amdgcn_mfma_f32_16x16x32_f16(a1[i], b1[j], acc[i][j], 0, 0, 0);
    }

    // epilogue: C/D layout col=lane&15, row=quad*4+reg
    float av[8], dv[8];
    #pragma unroll
    for (int j = 0; j < 8; j++) {
        av[j] = a_s[col0 + j * 16 + l15];
        dv[j] = a_d[col0 + j * 16 + l15];
    }

    #pragma unroll
    for (int i = 0; i < 8; i++) {
        #pragma unroll
        for (int r = 0; r < 4; r++) {
            int gr = row0 + i * 16 + quad * 4 + r;
            float sA0 = 0.f, sD0 = 0.f, sA1 = 0.f, sD1 = 0.f;
            #pragma unroll
            for (int j = 0; j < 8; j++) {
                float v = acc[i][j][r];
                if (CHEAD == 64 && j >= 4) { sA1 += v * av[j]; sD1 += v * dv[j]; }
                else                       { sA0 += v * av[j]; sD0 += v * dv[j]; }
            }
            #pragma unroll
            for (int m = 1; m < 16; m <<= 1) {
                sA0 += __shfl_xor(sA0, m); sD0 += __shfl_xor(sD0, m);
                if (CHEAD == 64) { sA1 += __shfl_xor(sA1, m); sD1 += __shfl_xor(sD1, m); }
            }
            if (gr < NNODES) {
                u16* cp = C16 + (size_t)gr * N + col0 + l15;
                #pragma unroll
                for (int j = 0; j < 8; j++)
                    cp[j * 16] = f2h(acc[i][j][r]);
                if (l15 == 0) {
                    if (CHEAD == 64) {
                        int hd0 = col0 >> 6;
                        atomicAdd(asrc + gr * HEADS + hd0,     sA0);
                        atomicAdd(adst + gr * HEADS + hd0,     sD0);
                        atomicAdd(asrc + gr * HEADS + hd0 + 1, sA1);
                        atomicAdd(adst + gr * HEADS + hd0 + 1, sD1);
                    } else {
                        int hd = col0 / CHEAD;
                        atomicAdd(asrc + gr * HEADS + hd, sA0);
                        atomicAdd(adst + gr * HEADS + hd, sD0);
                    }
                }
            }
        }
    }
}

// ---------------- softmax + aggregation (r9/r11 form) -----------------------
// One block per node, 8 waves = 8 heads; h gathered as fp16 row-major.
// MODE 0: concat +bias +ELU -> SWIZZLED fp16 plane (next GEMM's A operand).
// MODE 1: LDS head-mean + bias -> fp32 out, coalesced store.
template<int C, int MODE>
__global__ __launch_bounds__(512) void agg_k(const u16* __restrict__ h16,
                                             const float* __restrict__ asrc,
                                             const float* __restrict__ adst,
                                             const int* __restrict__ rows,
                                             const int* __restrict__ esrc,
                                             const float* __restrict__ bias,
                                             u16* __restrict__ oh,
                                             float* __restrict__ outf) {
    constexpr int LPE = C / 4;
    constexpr int EPW = 64 / LPE;
    constexpr int U   = (LPE == 64) ? 16 : (LPE == 32) ? 12 : 8;
    __shared__ float red[MODE == 1 ? HEADS * 256 : 8];

    const int n    = blockIdx.x;
    const int hd   = threadIdx.x >> 6;
    const int lane = threadIdx.x & 63;
    const int sub  = lane / LPE;
    const int cl   = lane % LPE;
    const int beg = rows[n], end = rows[n + 1], deg = end - beg;
    const float ad = adst[n * HEADS + hd];

    float4 acc = {0.f, 0.f, 0.f, 0.f};

    auto gather = [&](int e, float pw, int cdeg) {
        for (int j = 0; j < cdeg; j += EPW * U) {
            int   sn[U]; float wg[U];
            #pragma unroll
            for (int u = 0; u < U; u++) {
                int idx = j + sub + EPW * u;
                int   ss = __shfl(e, idx);
                float ww = __shfl(pw, idx);
                bool ok = idx < cdeg;
                sn[u] = ok ? ss : 0;
                wg[u] = ok ? ww : 0.f;
            }
            h4 v[U];
            #pragma unroll
            for (int u = 0; u < U; u++)
                v[u] = *(const h4*)(h16 + (size_t)sn[u] * (HEADS * C) + hd * C + cl * 4);
            #pragma unroll
            for (int u = 0; u < U; u++) {
                acc.x += wg[u] * (float)v[u].x; acc.y += wg[u] * (float)v[u].y;
                acc.z += wg[u] * (float)v[u].z; acc.w += wg[u] * (float)v[u].w;
            }
        }
    };

    if (deg <= 64) {
        int e = 0; float p = 0.f;
        if (lane < deg) {
            e = esrc[beg + lane];
            float lg = asrc[e * HEADS + hd] + ad;
            lg = (lg > 0.f) ? lg : 0.2f * lg;
            p = __expf(lg);
        }
        float s = p;
        #pragma unroll
        for (int off = 32; off; off >>= 1) s += __shfl_xor(s, off);
        float pw = p / (s + 1e-16f);
        gather(e, pw, deg);
    } else {
        float ssum = 0.f;
        for (int i = beg + lane; i < end; i += 64) {
            float lg = asrc[esrc[i] * HEADS + hd] + ad;
            lg = (lg > 0.f) ? lg : 0.2f * lg;
            ssum += __expf(lg);
        }
        #pragma unroll
        for (int off = 32; off; off >>= 1) ssum += __shfl_xor(ssum, off);
        float inv = 1.f / (ssum + 1e-16f);
        for (int c0 = beg; c0 < end; c0 += 64) {
            int cdeg = min(64, end - c0);
            int e = 0; float pw = 0.f;
            if (lane < cdeg) {
                e = esrc[c0 + lane];
                float lg = asrc[e * HEADS + hd] + ad;
                lg = (lg > 0.f) ? lg : 0.2f * lg;
                pw = __expf(lg) * inv;
            }
            gather(e, pw, cdeg);
        }
    }

    #pragma unroll
    for (int m = LPE; m < 64; m <<= 1) {
        acc.x += __shfl_xor(acc.x, m); acc.y += __shfl_xor(acc.y, m);
        acc.z += __shfl_xor(acc.z, m); acc.w += __shfl_xor(acc.w, m);
    }

    if constexpr (MODE == 0) {
        if (sub == 0) {
            const float* bp = bias + hd * C + cl * 4;
            float4 b = *(const float4*)bp;
            float r[4] = {acc.x + b.x, acc.y + b.y, acc.z + b.z, acc.w + b.w};
            #pragma unroll
            for (int j = 0; j < 4; j++)
                r[j] = (r[j] > 0.f) ? r[j] : (expf(r[j]) - 1.f);   // ELU
            ushort4 hv;
            hv.x = f2h(r[0]); hv.y = f2h(r[1]); hv.z = f2h(r[2]); hv.w = f2h(r[3]);
            // swizzled (fragment-major) store for next GEMM's A operand
            constexpr int KTO = (HEADS * C) / 32;
            int c0 = hd * C + cl * 4;
            int tr = n >> 4;
            int tk = c0 >> 5;
            int ln = ((c0 >> 3) & 3) * 16 + (n & 15);
            size_t idx = ((size_t)(tr * KTO + tk) * 64 + ln) * 8 + (c0 & 7);
            *(ushort4*)(oh + idx) = hv;
        }
    } else {
        *(float4*)&red[hd * 256 + lane * 4] = acc;
        __syncthreads();
        int tid = threadIdx.x;
        if (tid < 256) {
            float s = 0.f;
            #pragma unroll
            for (int hh = 0; hh < HEADS; hh++) s += red[hh * 256 + tid];
            outf[(size_t)n * 256 + tid] = s * 0.125f + bias[tid];
        }
    }
}

// ---------------- launch ----------------
extern "C" void kernel_launch(void* const* d_in, const int* in_sizes, int n_in,
                              void* d_out, int out_size, void* d_ws, size_t ws_size,
                              hipStream_t stream) {
    const float* x   = (const float*)d_in[0];
    const int*   ei  = (const int*)d_in[1];
    const float* W1  = (const float*)d_in[2];
    const float* as1 = (const float*)d_in[3];
    const float* ad1 = (const float*)d_in[4];
    const float* b1  = (const float*)d_in[5];
    const float* W2  = (const float*)d_in[6];
    const float* as2 = (const float*)d_in[7];
    const float* ad2 = (const float*)d_in[8];
    const float* b2  = (const float*)d_in[9];
    const float* W3  = (const float*)d_in[10];
    const float* as3 = (const float*)d_in[11];
    const float* ad3 = (const float*)d_in[12];
    const float* b3  = (const float*)d_in[13];
    float* out = (float*)d_out;

    // zero region (ONE memset): deg | cursor | asrc/adst x3 layers
    int*   deg    = (int*)d_ws;              // 10240
    int*   cursor = deg + 10240;             // 10240
    float* az     = (float*)(cursor + 10240);
    float* asrc1 = az,           * adst1 = az + 81920;
    float* asrc2 = az + 163840,  * adst2 = az + 245760;
    float* asrc3 = az + 327680,  * adst3 = az + 409600;
    int*   rows   = (int*)(az + 491520);     // 10240
    int*   esrc   = rows + 10240;            // 170240
    u16*   Hh     = (u16*)(esrc + 170240);   // fp16 h row-major, up to 10000*2048
    u16*   Af     = Hh + (size_t)NNODES * 2048;   // swizzled activations, up to 10000*1024
    u16*   Axs    = Af + (size_t)NNODES * 1024;   // swizzled x, 10000*256
    u16*   W1s    = Axs + (size_t)NNODES * 256;   // 512*256
    u16*   W2s    = W1s + 512 * 256;              // 1024*512
    u16*   W3s    = W2s + 1024 * 512;             // 2048*1024

    hipMemsetAsync(d_ws, 0, (size_t)(20480 + 491520) * 4, stream);

    count_k<<<(TOT_E + 255) / 256, 256, 0, stream>>>(ei, deg);
    scan_k<<<1, 1024, 0, stream>>>(deg, rows);
    scatter_k<<<(TOT_E + 255) / 256, 256, 0, stream>>>(ei, rows, cursor, esrc);
    cvtsw_all<<<2594, 256, 0, stream>>>(x, W1, W2, W3, Axs, W1s, W2s, W3s);

    // ---- layer 1: IN=256 -> 8x64 concat ----
    gemm_dx<64><<<dim3(4, 79), 64, 0, stream>>>(Axs, W1s, Hh, 512, 256,
                                                as1, ad1, asrc1, adst1);
    agg_k<64, 0><<<NNODES, 512, 0, stream>>>(Hh, asrc1, adst1, rows, esrc, b1, Af, nullptr);

    // ---- layer 2: 512 -> 8x128 concat ----
    gemm_dx<128><<<dim3(8, 79), 64, 0, stream>>>(Af, W2s, Hh, 1024, 512,
                                                 as2, ad2, asrc2, adst2);
    agg_k<128, 0><<<NNODES, 512, 0, stream>>>(Hh, asrc2, adst2, rows, esrc, b2, Af, nullptr);

    // ---- layer 3: 1024 -> 8x256 mean ----
    gemm_dx<256><<<dim3(16, 79), 64, 0, stream>>>(Af, W3s, Hh, 2048, 1024,
                                                  as3, ad3, asrc3, adst3);
    agg_k<256, 1><<<NNODES, 512, 0, stream>>>(Hh, asrc3, adst3, rows, esrc, b3, nullptr, out);
}

// Round 13
// 438.921 us; speedup vs baseline: 1.1448x; 1.1448x over previous
//
#include <hip/hip_runtime.h>
#include <cstdint>

#define NNODES 10000
#define NEDGES 160000
#define TOT_E  (NEDGES + NNODES)
#define HEADS  8

typedef unsigned short u16;
typedef __attribute__((ext_vector_type(8))) _Float16 h8;   // 8 fp16 (16B)
typedef __attribute__((ext_vector_type(4))) _Float16 h4;   // 4 fp16 (8B)
typedef __attribute__((ext_vector_type(4))) float f4;      // MFMA accumulator

// s_waitcnt imm: [3:0] vmcnt_lo, [6:4] expcnt, [11:8] lgkmcnt, [15:14] vmcnt_hi
#define WAIT_VM(n) __builtin_amdgcn_s_waitcnt(0x0F70 | (n))   // vmcnt(n), lgkm/exp no-wait

__device__ inline u16 f2h(float x) {
    union { _Float16 h; u16 u; } c; c.h = (_Float16)x; return c.u;
}

__device__ inline void gld16(const u16* g, u16* l) {
    __builtin_amdgcn_global_load_lds(
        (const __attribute__((address_space(1))) void*)g,
        (__attribute__((address_space(3))) void*)l, 16, 0, 0);
}

// ---------------- CSR build (dst-sorted) ----------------
__global__ void count_k(const int* __restrict__ ei, int* __restrict__ deg) {
    int i = blockIdx.x * 256 + threadIdx.x;
    if (i >= TOT_E) return;
    int dst = (i < NEDGES) ? ei[NEDGES + i] : (i - NEDGES);
    atomicAdd(deg + dst, 1);
}

__global__ __launch_bounds__(1024) void scan_k(const int* __restrict__ deg,
                                               int* __restrict__ rows) {
    __shared__ int buf[1024];
    int tid = threadIdx.x;
    int base = tid * 10;
    int loc[10]; int s = 0;
    #pragma unroll
    for (int j = 0; j < 10; j++) {
        int i = base + j;
        loc[j] = s;
        s += (i < NNODES) ? deg[i] : 0;
    }
    buf[tid] = s;
    __syncthreads();
    for (int off = 1; off < 1024; off <<= 1) {
        int t = (tid >= off) ? buf[tid - off] : 0;
        __syncthreads();
        buf[tid] += t;
        __syncthreads();
    }
    int ex = tid ? buf[tid - 1] : 0;
    #pragma unroll
    for (int j = 0; j < 10; j++) {
        int i = base + j;
        if (i < NNODES) rows[i] = ex + loc[j];
    }
    if (tid == 1023) rows[NNODES] = buf[1023];
}

__global__ void scatter_k(const int* __restrict__ ei, const int* __restrict__ rows,
                          int* __restrict__ cursor, int* __restrict__ esrc) {
    int i = blockIdx.x * 256 + threadIdx.x;
    if (i >= TOT_E) return;
    int src, dst;
    if (i < NEDGES) { src = ei[i]; dst = ei[NEDGES + i]; }
    else            { src = i - NEDGES; dst = src; }
    int pos = atomicAdd(cursor + dst, 1);
    esrc[rows[dst] + pos] = src;
}

// ---------------- merged fp32 -> fp16 convert (x, W1, W2, W3 row-major) -----
__device__ inline void cvt4(const float* __restrict__ in, u16* __restrict__ o, int i) {
    float4 v = ((const float4*)in)[i];
    ushort4 h{f2h(v.x), f2h(v.y), f2h(v.z), f2h(v.w)};
    ((ushort4*)o)[i] = h;
}
__global__ __launch_bounds__(256) void cvt_all(const float* __restrict__ x,
        const float* __restrict__ W1, const float* __restrict__ W2,
        const float* __restrict__ W3, u16* __restrict__ xf, u16* __restrict__ W1f,
        u16* __restrict__ W2f, u16* __restrict__ W3f) {
    int g = blockIdx.x * 256 + threadIdx.x;
    if (g < 640000)       cvt4(x,  xf,  g);
    else if (g < 672768)  cvt4(W1, W1f, g - 640000);
    else if (g < 803840)  cvt4(W2, W2f, g - 672768);
    else if (g < 1328128) cvt4(W3, W3f, g - 803840);
}

// ---------------- fp16 MFMA GEMM: 256x128 block, 4 waves of 64x128 ---------
// C16[M,N] = fp16( A[M,K] * W[N,K]^T ). BK=32, triple-buffered LDS (3x24KB),
// prefetch depth 2 (r11-verified WAIT_VM pattern, 6 gld16/iter -> 12/6/0).
// Per-wave tile 64x128: 12 ds_read_b128 per 32 MFMAs (0.375 reads/MFMA vs 0.5
// at 64x64) — attacks the measured LDS-read-throughput bound of r7-r11.
// acc[4][8] = 128 VGPRs; __launch_bounds__(256,2) caps regs for 2 waves/SIMD.
// 4-oct XOR swizzle (r11-verified): stage oct (lane&3)^((lane>>3)&3), read
// oct quad^((l15>>1)&3) -> conflict-free. Epilogue: fp16 C + alpha partials.
template<int CHEAD>
__global__ __launch_bounds__(256, 2) void gemm_f16(
    const u16* __restrict__ A, const u16* __restrict__ B,
    u16* __restrict__ C16, int M, int N, int K,
    const float* __restrict__ a_s, const float* __restrict__ a_d,
    float* __restrict__ asrc, float* __restrict__ adst)
{
    __shared__ u16 sh[3][12288];              // [buf][A:0..8191 | B:8192..12287]
    const int t = threadIdx.x, lane = t & 63, w = t >> 6;
    const int row0 = blockIdx.y * 256, col0 = blockIdx.x * 128;
    const int l15 = lane & 15, quad = lane >> 4;

    // staging: 24 chunks of 16 rows x 32 cols (1 KB); A: c=0..15, B: c=16..23.
    // wave w stages chunks 6w..6w+5; lane = row lane>>2, swizzled oct.
    const int octg = (lane & 3) ^ ((lane >> 3) & 3);
    const int rl   = lane >> 2;               // 0..15
    const u16* gp[6]; int lofs[6];
    #pragma unroll
    for (int q = 0; q < 6; q++) {
        int c = w * 6 + q;
        if (c < 16) {
            int gr = row0 + c * 16 + rl; if (gr >= M) gr = M - 1;
            gp[q] = A + (size_t)gr * K + octg * 8;
            lofs[q] = c * 512;
        } else {
            int gc = col0 + (c - 16) * 16 + rl;   // N mult of 128 -> in bounds
            gp[q] = B + (size_t)gc * K + octg * 8;
            lofs[q] = 8192 + (c - 16) * 512;
        }
    }

    const int sw = (l15 >> 1) & 3;
    const int po = (quad ^ sw) * 8;           // swizzled physical oct (read)
    const int arow = (w * 64 + l15) * 32;     // wave's 64-row strip of A
    const int brow = 8192 + l15 * 32;

    f4 acc[4][8];
    #pragma unroll
    for (int i = 0; i < 4; i++)
        #pragma unroll
        for (int j = 0; j < 8; j++)
            acc[i][j] = (f4){0.f, 0.f, 0.f, 0.f};

    const int T = K >> 5;

    // prologue: stage tiles 0,1 into bufs 0,1
    #pragma unroll
    for (int q = 0; q < 6; q++) { gld16(gp[q], &sh[0][lofs[q]]); gp[q] += 32; }
    #pragma unroll
    for (int q = 0; q < 6; q++) { gld16(gp[q], &sh[1][lofs[q]]); gp[q] += 32; }

    for (int k = 0; k < T; k++) {
        if (k + 2 < T) {
            u16* dst = &sh[(k + 2) % 3][0];
            #pragma unroll
            for (int q = 0; q < 6; q++) { gld16(gp[q], dst + lofs[q]); gp[q] += 32; }
            WAIT_VM(12);                      // tile k landed; k+1,k+2 in flight
        } else if (k + 2 == T) {
            WAIT_VM(6);                       // tile k landed; k+1 in flight
        } else {
            WAIT_VM(0);
        }
        __builtin_amdgcn_s_barrier();         // raw: no compiler vmcnt(0) drain

        const u16* sa = &sh[k % 3][0];
        h8 a[4];
        #pragma unroll
        for (int i = 0; i < 4; i++)
            a[i] = *(const h8*)&sa[arow + i * 512 + po];
        #pragma unroll
        for (int j = 0; j < 8; j++) {
            h8 b = *(const h8*)&sa[brow + j * 512 + po];
            #pragma unroll
            for (int i = 0; i < 4; i++)
                acc[i][j] = __builtin_amdgcn_mfma_f32_16x16x32_f16(a[i], b, acc[i][j], 0, 0, 0);
        }
        __builtin_amdgcn_s_barrier();         // reads done before buf reuse
    }

    // alpha coefficients for this block's 128-col span
    float av[8], dv[8];
    #pragma unroll
    for (int j = 0; j < 8; j++) {
        av[j] = a_s[col0 + j * 16 + l15];
        dv[j] = a_d[col0 + j * 16 + l15];
    }

    // epilogue: C/D layout col=lane&15, row=quad*4+reg
    #pragma unroll
    for (int i = 0; i < 4; i++) {
        #pragma unroll
        for (int r = 0; r < 4; r++) {
            int gr = row0 + w * 64 + i * 16 + quad * 4 + r;
            float sA0 = 0.f, sD0 = 0.f, sA1 = 0.f, sD1 = 0.f;
            #pragma unroll
            for (int j = 0; j < 8; j++) {
                float v = acc[i][j][r];
                if (CHEAD == 64 && j >= 4) { sA1 += v * av[j]; sD1 += v * dv[j]; }
                else                       { sA0 += v * av[j]; sD0 += v * dv[j]; }
            }
            #pragma unroll
            for (int m = 1; m < 16; m <<= 1) {
                sA0 += __shfl_xor(sA0, m); sD0 += __shfl_xor(sD0, m);
                if (CHEAD == 64) { sA1 += __shfl_xor(sA1, m); sD1 += __shfl_xor(sD1, m); }
            }
            if (gr < M) {
                u16* cp = C16 + (size_t)gr * N + col0 + l15;
                #pragma unroll
                for (int j = 0; j < 8; j++)
                    cp[j * 16] = f2h(acc[i][j][r]);
                if (l15 == 0) {
                    if (CHEAD == 64) {
                        int hd0 = col0 >> 6;
                        atomicAdd(asrc + gr * HEADS + hd0,     sA0);
                        atomicAdd(adst + gr * HEADS + hd0,     sD0);
                        atomicAdd(asrc + gr * HEADS + hd0 + 1, sA1);
                        atomicAdd(adst + gr * HEADS + hd0 + 1, sD1);
                    } else {
                        int hd = col0 / CHEAD;
                        atomicAdd(asrc + gr * HEADS + hd, sA0);
                        atomicAdd(adst + gr * HEADS + hd, sD0);
                    }
                }
            }
        }
    }
}

// ---------------- softmax + aggregation (r9/r11 verified form) --------------
// One block per node, 8 waves = 8 heads; h gathered as fp16 row-major.
// No max-subtraction (logits bounded; p/s scale-invariant). LPE = C/4 lanes
// per edge (8B h4 loads), U batched edge-passes in flight.
// MODE 0: concat +bias +ELU -> fp16 plane. MODE 1: LDS head-mean + bias.
template<int C, int MODE>
__global__ __launch_bounds__(512) void agg_k(const u16* __restrict__ h16,
                                             const float* __restrict__ asrc,
                                             const float* __restrict__ adst,
                                             const int* __restrict__ rows,
                                             const int* __restrict__ esrc,
                                             const float* __restrict__ bias,
                                             u16* __restrict__ oh,
                                             float* __restrict__ outf) {
    constexpr int LPE = C / 4;
    constexpr int EPW = 64 / LPE;
    constexpr int U   = (LPE == 64) ? 16 : (LPE == 32) ? 12 : 8;
    __shared__ float red[MODE == 1 ? HEADS * 256 : 8];

    const int n    = blockIdx.x;
    const int hd   = threadIdx.x >> 6;
    const int lane = threadIdx.x & 63;
    const int sub  = lane / LPE;
    const int cl   = lane % LPE;
    const int beg = rows[n], end = rows[n + 1], deg = end - beg;
    const float ad = adst[n * HEADS + hd];

    float4 acc = {0.f, 0.f, 0.f, 0.f};

    auto gather = [&](int e, float pw, int cdeg) {
        for (int j = 0; j < cdeg; j += EPW * U) {
            int   sn[U]; float wg[U];
            #pragma unroll
            for (int u = 0; u < U; u++) {
                int idx = j + sub + EPW * u;
                int   ss = __shfl(e, idx);
                float ww = __shfl(pw, idx);
                bool ok = idx < cdeg;
                sn[u] = ok ? ss : 0;
                wg[u] = ok ? ww : 0.f;
            }
            h4 v[U];
            #pragma unroll
            for (int u = 0; u < U; u++)
                v[u] = *(const h4*)(h16 + (size_t)sn[u] * (HEADS * C) + hd * C + cl * 4);
            #pragma unroll
            for (int u = 0; u < U; u++) {
                acc.x += wg[u] * (float)v[u].x; acc.y += wg[u] * (float)v[u].y;
                acc.z += wg[u] * (float)v[u].z; acc.w += wg[u] * (float)v[u].w;
            }
        }
    };

    if (deg <= 64) {
        int e = 0; float p = 0.f;
        if (lane < deg) {
            e = esrc[beg + lane];
            float lg = asrc[e * HEADS + hd] + ad;
            lg = (lg > 0.f) ? lg : 0.2f * lg;
            p = __expf(lg);
        }
        float s = p;
        #pragma unroll
        for (int off = 32; off; off >>= 1) s += __shfl_xor(s, off);
        float pw = p / (s + 1e-16f);
        gather(e, pw, deg);
    } else {
        float ssum = 0.f;
        for (int i = beg + lane; i < end; i += 64) {
            float lg = asrc[esrc[i] * HEADS + hd] + ad;
            lg = (lg > 0.f) ? lg : 0.2f * lg;
            ssum += __expf(lg);
        }
        #pragma unroll
        for (int off = 32; off; off >>= 1) ssum += __shfl_xor(ssum, off);
        float inv = 1.f / (ssum + 1e-16f);
        for (int c0 = beg; c0 < end; c0 += 64) {
            int cdeg = min(64, end - c0);
            int e = 0; float pw = 0.f;
            if (lane < cdeg) {
                e = esrc[c0 + lane];
                float lg = asrc[e * HEADS + hd] + ad;
                lg = (lg > 0.f) ? lg : 0.2f * lg;
                pw = __expf(lg) * inv;
            }
            gather(e, pw, cdeg);
        }
    }

    #pragma unroll
    for (int m = LPE; m < 64; m <<= 1) {
        acc.x += __shfl_xor(acc.x, m); acc.y += __shfl_xor(acc.y, m);
        acc.z += __shfl_xor(acc.z, m); acc.w += __shfl_xor(acc.w, m);
    }

    if constexpr (MODE == 0) {
        if (sub == 0) {
            const float* bp = bias + hd * C + cl * 4;
            float4 b = *(const float4*)bp;
            float r[4] = {acc.x + b.x, acc.y + b.y, acc.z + b.z, acc.w + b.w};
            #pragma unroll
            for (int j = 0; j < 4; j++)
                r[j] = (r[j] > 0.f) ? r[j] : (expf(r[j]) - 1.f);   // ELU
            ushort4 hv;
            hv.x = f2h(r[0]); hv.y = f2h(r[1]); hv.z = f2h(r[2]); hv.w = f2h(r[3]);
            *(ushort4*)(oh + (size_t)n * (HEADS * C) + hd * C + cl * 4) = hv;
        }
    } else {
        *(float4*)&red[hd * 256 + lane * 4] = acc;
        __syncthreads();
        int tid = threadIdx.x;
        if (tid < 256) {
            float s = 0.f;
            #pragma unroll
            for (int hh = 0; hh < HEADS; hh++) s += red[hh * 256 + tid];
            outf[(size_t)n * 256 + tid] = s * 0.125f + bias[tid];
        }
    }
}

// ---------------- launch ----------------
extern "C" void kernel_launch(void* const* d_in, const int* in_sizes, int n_in,
                              void* d_out, int out_size, void* d_ws, size_t ws_size,
                              hipStream_t stream) {
    const float* x   = (const float*)d_in[0];
    const int*   ei  = (const int*)d_in[1];
    const float* W1  = (const float*)d_in[2];
    const float* as1 = (const float*)d_in[3];
    const float* ad1 = (const float*)d_in[4];
    const float* b1  = (const float*)d_in[5];
    const float* W2  = (const float*)d_in[6];
    const float* as2 = (const float*)d_in[7];
    const float* ad2 = (const float*)d_in[8];
    const float* b2  = (const float*)d_in[9];
    const float* W3  = (const float*)d_in[10];
    const float* as3 = (const float*)d_in[11];
    const float* ad3 = (const float*)d_in[12];
    const float* b3  = (const float*)d_in[13];
    float* out = (float*)d_out;

    // zero region (ONE memset): deg | cursor | asrc/adst x3 layers
    int*   deg    = (int*)d_ws;              // 10240
    int*   cursor = deg + 10240;             // 10240
    float* az     = (float*)(cursor + 10240);
    float* asrc1 = az,           * adst1 = az + 81920;
    float* asrc2 = az + 163840,  * adst2 = az + 245760;
    float* asrc3 = az + 327680,  * adst3 = az + 409600;
    int*   rows   = (int*)(az + 491520);     // 10240
    int*   esrc   = rows + 10240;            // 170240
    u16*   Hh     = (u16*)(esrc + 170240);   // fp16 h row-major, up to 10000*2048
    u16*   Af     = Hh + (size_t)NNODES * 2048;   // fp16 activations (row-major)
    u16*   Axf    = Af + (size_t)NNODES * 1024;   // fp16 x, 10000*256
    u16*   W1f    = Axf + (size_t)NNODES * 256;   // 512*256
    u16*   W2f    = W1f + 512 * 256;              // 1024*512
    u16*   W3f    = W2f + 1024 * 512;             // 2048*1024

    hipMemsetAsync(d_ws, 0, (size_t)(20480 + 491520) * 4, stream);

    count_k<<<(TOT_E + 255) / 256, 256, 0, stream>>>(ei, deg);
    scan_k<<<1, 1024, 0, stream>>>(deg, rows);
    scatter_k<<<(TOT_E + 255) / 256, 256, 0, stream>>>(ei, rows, cursor, esrc);
    cvt_all<<<(1328128 + 255) / 256, 256, 0, stream>>>(x, W1, W2, W3, Axf, W1f, W2f, W3f);

    const int rb = (NNODES + 255) / 256;     // 40 row-blocks

    // ---- layer 1: IN=256 -> 8x64 concat ----
    gemm_f16<64><<<dim3(4, rb), 256, 0, stream>>>(Axf, W1f, Hh, NNODES, 512, 256,
                                                  as1, ad1, asrc1, adst1);
    agg_k<64, 0><<<NNODES, 512, 0, stream>>>(Hh, asrc1, adst1, rows, esrc, b1, Af, nullptr);

    // ---- layer 2: 512 -> 8x128 concat ----
    gemm_f16<128><<<dim3(8, rb), 256, 0, stream>>>(Af, W2f, Hh, NNODES, 1024, 512,
                                                   as2, ad2, asrc2, adst2);
    agg_k<128, 0><<<NNODES, 512, 0, stream>>>(Hh, asrc2, adst2, rows, esrc, b2, Af, nullptr);

    // ---- layer 3: 1024 -> 8x256 mean ----
    gemm_f16<256><<<dim3(16, rb), 256, 0, stream>>>(Af, W3f, Hh, NNODES, 2048, 1024,
                                                    as3, ad3, asrc3, adst3);
    agg_k<256, 1><<<NNODES, 512, 0, stream>>>(Hh, asrc3, adst3, rows, esrc, b3, nullptr, out);
}